// Round 15
// baseline (202.793 us; speedup 1.0000x reference)
//
#include <hip/hip_runtime.h>
#include <hip/hip_cooperative_groups.h>
#include <cmath>

namespace cg = cooperative_groups;

#define B_  2
#define L_  1024
#define DM  1024
#define DI  2048
#define DS  16
#define DR  64
#define NC  32         // scan time-chunks
#define CL  (L_/NC)    // 32 steps per chunk

typedef __attribute__((ext_vector_type(8))) short short8;
typedef __attribute__((ext_vector_type(4))) float f32x4;

static __device__ __forceinline__ ushort f2bf(float f) {
    union { float f; unsigned u; } c; c.f = f;
    unsigned u = c.u;
    return (ushort)((u + 0x7fffu + ((u >> 16) & 1u)) >> 16);   // RNE
}
static __device__ __forceinline__ float bf2f(ushort h) {
    union { unsigned u; float f; } c; c.u = ((unsigned)h) << 16;
    return c.f;
}

static __device__ __forceinline__ float softplus_f(float v) {
    return (v > 20.f) ? v : log1pf(__expf(v));
}

// ---------------------------------------------------------------------------
// bt_body: transpose-convert one 32x32 tile of fp32 [K][N] -> bf16 [N][K].
// ---------------------------------------------------------------------------
static __device__ void bt_body(const float* __restrict__ in,
                               ushort* __restrict__ oh, ushort* __restrict__ ol,
                               int K, int N, int Npad, int bx, int by,
                               float (*t)[33])
{
    const int tid = threadIdx.x;
    const int tx = tid & 31, ty = tid >> 5;
    const int n0 = bx * 32, k0 = by * 32;
    #pragma unroll
    for (int i = 0; i < 4; ++i) {
        int k = k0 + ty * 4 + i, n = n0 + tx;
        t[ty * 4 + i][tx] = (n < N) ? in[(size_t)k * N + n] : 0.f;
    }
    __syncthreads();
    #pragma unroll
    for (int i = 0; i < 4; ++i) {
        int r = n0 + ty * 4 + i;
        int c = k0 + tx;
        if (r < Npad) {
            float v = t[tx][ty * 4 + i];
            ushort h = f2bf(v);
            oh[(size_t)r * K + c] = h;
            if (ol) ol[(size_t)r * K + c] = f2bf(v - bf2f(h));
        }
    }
}

// ---------------------------------------------------------------------------
__global__ __launch_bounds__(256) void prep_all(
    const float* __restrict__ x, const float* __restrict__ W_in,
    const float* __restrict__ W_xprj, const float* __restrict__ W_dt,
    const float* __restrict__ W_out,
    ushort* __restrict__ Xh, ushort* __restrict__ WIh,
    ushort* __restrict__ WXh, ushort* __restrict__ WXl,
    ushort* __restrict__ WDh, ushort* __restrict__ WDl,
    ushort* __restrict__ Woh)
{
    __shared__ float t[32][33];
    int blk = blockIdx.x;
    if (blk < 4096) {
        bt_body(W_in, WIh, nullptr, 1024, 4096, 4096, blk & 127, blk >> 7, t);
    } else if (blk < 4352) {
        int b2 = blk - 4096;
        bt_body(W_xprj, WXh, WXl, 2048, 96, 128, b2 & 3, b2 >> 2, t);
    } else if (blk < 4480) {
        int b2 = blk - 4352;
        bt_body(W_dt, WDh, WDl, 64, 2048, 2048, b2 & 63, b2 >> 6, t);
    } else if (blk < 5504) {
        int v = (blk - 4480) * 256 + threadIdx.x;    // over 262144
        int r  = v >> 7;
        int c8 = v & 127;
        const float* p = x + (size_t)r * DM + c8 * 8;
        float4 v0 = *(const float4*)p;
        float4 v1 = *(const float4*)(p + 4);
        float vv[8] = {v0.x, v0.y, v0.z, v0.w, v1.x, v1.y, v1.z, v1.w};
        unsigned h[4];
        #pragma unroll
        for (int j = 0; j < 4; ++j)
            h[j] = (unsigned)f2bf(vv[2*j]) | ((unsigned)f2bf(vv[2*j+1]) << 16);
        size_t o = (size_t)r * 1024 + c8 * 8;
        *(uint4*)&Xh[o] = make_uint4(h[0], h[1], h[2], h[3]);
    } else {
        int b2 = blk - 5504;
        bt_body(W_out, Woh, nullptr, 2048, 1024, 1024, b2 & 31, b2 >> 5, t);
    }
}

// ---------------------------------------------------------------------------
// GEMM building blocks (XOR-swizzle involution on both sides).
// ---------------------------------------------------------------------------
static __device__ __forceinline__ void stage_tile(
    ushort* lds, const ushort* __restrict__ g, int ld, int row0, int k0,
    int wid, int lane)
{
    #pragma unroll
    for (int it = 0; it < 2; ++it) {
        int o  = wid * 2048 + it * 1024;
        int ob = o + lane * 16;
        int a  = ob ^ (((ob >> 7) & 7) << 4);
        int row = a >> 6;
        int lc  = (a >> 4) & 3;
        const ushort* gp = g + (size_t)(row0 + row) * ld + k0 + lc * 8;
        __builtin_amdgcn_global_load_lds(
            (const __attribute__((address_space(1))) void*)gp,
            (__attribute__((address_space(3))) void*)((char*)lds + o),
            16, 0, 0);
    }
}

static __device__ __forceinline__ void stage_tile64(
    ushort* lds, const ushort* __restrict__ g, int ld, int row0, int k0,
    int wid, int lane)
{
    int o  = wid * 1024;
    int ob = o + lane * 16;
    int a  = ob ^ (((ob >> 7) & 7) << 4);
    int row = a >> 6;
    int lc  = (a >> 4) & 3;
    const ushort* gp = g + (size_t)(row0 + row) * ld + k0 + lc * 8;
    __builtin_amdgcn_global_load_lds(
        (const __attribute__((address_space(1))) void*)gp,
        (__attribute__((address_space(3))) void*)((char*)lds + o),
        16, 0, 0);
}

static __device__ __forceinline__ short8 frag(const ushort* lds, int row, int fq) {
    int a = row * 64 + fq * 16;
    int b = a ^ (((a >> 7) & 7) << 4);
    return *(const short8*)((const char*)lds + b);
}

template<int TERMS>
static __device__ __forceinline__ void stage_all(
    ushort* buf, const ushort* Ah, const ushort* Bh, const ushort* Bl,
    int lda, int ldb, int bm, int bn, int k, int wid, int lane)
{
    stage_tile(buf,        Ah, lda, bm, k, wid, lane);
    stage_tile(buf + 4096, Bh, ldb, bn, k, wid, lane);
    if (TERMS == 2) stage_tile(buf + 8192, Bl, ldb, bn, k, wid, lane);
}

template<int TERMS>
static __device__ __forceinline__ void compute_tile(
    const ushort* buf, int wr, int wc, int fr, int fq, f32x4 acc[4][4])
{
    const ushort* sAh = buf;
    const ushort* sBh = buf + 4096;
    const ushort* sBl = buf + 8192;
    short8 a_h[4], b_h[4], b_l[4];
    #pragma unroll
    for (int m = 0; m < 4; ++m)
        a_h[m] = frag(sAh, wr + m * 16 + fr, fq);
    #pragma unroll
    for (int n = 0; n < 4; ++n) {
        b_h[n] = frag(sBh, wc + n * 16 + fr, fq);
        if (TERMS == 2) b_l[n] = frag(sBl, wc + n * 16 + fr, fq);
    }
    #pragma unroll
    for (int m = 0; m < 4; ++m)
        #pragma unroll
        for (int n = 0; n < 4; ++n) {
            acc[m][n] = __builtin_amdgcn_mfma_f32_16x16x32_bf16(a_h[m], b_h[n], acc[m][n], 0, 0, 0);
            if (TERMS == 2)
                acc[m][n] = __builtin_amdgcn_mfma_f32_16x16x32_bf16(a_h[m], b_l[n], acc[m][n], 0, 0, 0);
        }
}

// ---------------------------------------------------------------------------
// dev_gemm: 128x128 tile GEMM body. Leading __syncthreads protects the LDS
// arena when called in a loop. EPI semantics as before.
// ---------------------------------------------------------------------------
template<int TERMS, int EPI>
static __device__ void dev_gemm(
    ushort* sm, const ushort* __restrict__ Ah,
    const ushort* __restrict__ Bh, const ushort* __restrict__ Bl,
    float* __restrict__ C, ushort* __restrict__ oh,
    const float* __restrict__ bvec,
    int M, int N, int lda, int ldb, int ldc, int kspl,
    int bm, int bn, int kb, int zi)
{
    constexpr int TILE = TERMS == 1 ? 8192 : 12288;
    const int tid = threadIdx.x, wid = tid >> 6, lane = tid & 63;
    const int wr = (wid >> 1) * 64, wc = (wid & 1) * 64;
    const int fr = lane & 15, fq = lane >> 4;

    __syncthreads();
    f32x4 acc[4][4] = {};

    stage_all<TERMS>(sm, Ah, Bh, Bl, lda, ldb, bm, bn, kb, wid, lane);
    __syncthreads();
    int cur = 0;
    for (int k0 = 32; k0 < kspl; k0 += 32) {
        ushort* nbuf       = cur ? sm : sm + TILE;
        const ushort* cbuf = cur ? sm + TILE : sm;
        stage_all<TERMS>(nbuf, Ah, Bh, Bl, lda, ldb, bm, bn, kb + k0, wid, lane);
        compute_tile<TERMS>(cbuf, wr, wc, fr, fq, acc);
        __syncthreads();
        cur ^= 1;
    }
    compute_tile<TERMS>(cur ? sm + TILE : sm, wr, wc, fr, fq, acc);

    #pragma unroll
    for (int m = 0; m < 4; ++m) {
        int rbase = bm + wr + m * 16 + fq * 4;
        #pragma unroll
        for (int n = 0; n < 4; ++n) {
            int col = bn + wc + n * 16 + fr;
            if (col >= N) continue;
            if (EPI == 0) {
                #pragma unroll
                for (int j = 0; j < 4; ++j)
                    C[((size_t)zi * M + rbase + j) * ldc + col] = acc[m][n][j];
            } else if (EPI == 1) {
                float bb = bvec[col];
                #pragma unroll
                for (int j = 0; j < 4; ++j)
                    oh[(size_t)(rbase + j) * ldc + col] =
                        f2bf(softplus_f(acc[m][n][j] + bb));
            } else {
                if (col < 2048) {
                    #pragma unroll
                    for (int j = 0; j < 4; ++j)
                        C[(size_t)(rbase + j) * 2048 + col] = acc[m][n][j];
                } else {
                    #pragma unroll
                    for (int j = 0; j < 4; ++j)
                        oh[(size_t)(rbase + j) * 2048 + (col - 2048)] =
                            f2bf(acc[m][n][j]);
                }
            }
        }
    }
}

// ---------------------------------------------------------------------------
// dev_gemm_out: 128x64 tile, full-K, 1-term, direct fp32 store.
// ---------------------------------------------------------------------------
static __device__ void dev_gemm_out(
    ushort* sm, const ushort* __restrict__ Ah, const ushort* __restrict__ Bh,
    float* __restrict__ C, int K, int lda, int ldb, int ldc, int bm, int bn)
{
    const int tid = threadIdx.x, wid = tid >> 6, lane = tid & 63;
    const int wr = (wid >> 1) * 64, wc = (wid & 1) * 32;
    const int fr = lane & 15, fq = lane >> 4;

    __syncthreads();
    f32x4 acc[4][2] = {};

    stage_tile  (sm,        Ah, lda, bm, 0, wid, lane);
    stage_tile64(sm + 4096, Bh, ldb, bn, 0, wid, lane);
    __syncthreads();
    int cur = 0;
    for (int k0 = 32; k0 < K; k0 += 32) {
        ushort* nbuf       = cur ? sm : sm + 6144;
        const ushort* cbuf = cur ? sm + 6144 : sm;
        stage_tile  (nbuf,        Ah, lda, bm, k0, wid, lane);
        stage_tile64(nbuf + 4096, Bh, ldb, bn, k0, wid, lane);
        {
            short8 a_h[4], b_h[2];
            #pragma unroll
            for (int m = 0; m < 4; ++m)
                a_h[m] = frag(cbuf, wr + m * 16 + fr, fq);
            #pragma unroll
            for (int n = 0; n < 2; ++n)
                b_h[n] = frag(cbuf + 4096, wc + n * 16 + fr, fq);
            #pragma unroll
            for (int m = 0; m < 4; ++m)
                #pragma unroll
                for (int n = 0; n < 2; ++n)
                    acc[m][n] = __builtin_amdgcn_mfma_f32_16x16x32_bf16(a_h[m], b_h[n], acc[m][n], 0, 0, 0);
        }
        __syncthreads();
        cur ^= 1;
    }
    {
        const ushort* cbuf = cur ? sm + 6144 : sm;
        short8 a_h[4], b_h[2];
        #pragma unroll
        for (int m = 0; m < 4; ++m)
            a_h[m] = frag(cbuf, wr + m * 16 + fr, fq);
        #pragma unroll
        for (int n = 0; n < 2; ++n)
            b_h[n] = frag(cbuf + 4096, wc + n * 16 + fr, fq);
        #pragma unroll
        for (int m = 0; m < 4; ++m)
            #pragma unroll
            for (int n = 0; n < 2; ++n)
                acc[m][n] = __builtin_amdgcn_mfma_f32_16x16x32_bf16(a_h[m], b_h[n], acc[m][n], 0, 0, 0);
    }

    #pragma unroll
    for (int m = 0; m < 4; ++m) {
        int rbase = bm + wr + m * 16 + fq * 4;
        #pragma unroll
        for (int n = 0; n < 2; ++n) {
            int col = bn + wc + n * 16 + fr;
            #pragma unroll
            for (int j = 0; j < 4; ++j)
                C[(size_t)(rbase + j) * ldc + col] = acc[m][n][j];
        }
    }
}

// ---------------------------------------------------------------------------
// dev_scanA / dev_scanC: scan phase bodies (LDS arena passed in).
// ---------------------------------------------------------------------------
static __device__ void dev_scanA(
    float* Bs, const ushort* __restrict__ Dh, const ushort* __restrict__ uh,
    const float* __restrict__ xdbl, const float* __restrict__ A_log,
    float* __restrict__ sA, float* __restrict__ sH, int blk)
{
    const int tid  = threadIdx.x;
    const int dblk = blk & 7;
    const int c    = (blk >> 3) & (NC - 1);
    const int b    = blk >> 8;
    const int d    = dblk * 256 + tid;
    const int bl0  = b * L_ + c * CL;

    __syncthreads();
    for (int i = tid; i < CL * 16; i += 256) {
        int t = i >> 4, n = i & 15;
        Bs[t * 16 + n] = xdbl[(size_t)(bl0 + t) * 96 + DR + n];
    }
    __syncthreads();

    float Adn[16];
    #pragma unroll
    for (int q = 0; q < 4; ++q) {
        float4 al = *(const float4*)&A_log[d * DS + q * 4];
        Adn[q * 4 + 0] = -__expf(al.x);
        Adn[q * 4 + 1] = -__expf(al.y);
        Adn[q * 4 + 2] = -__expf(al.z);
        Adn[q * 4 + 3] = -__expf(al.w);
    }
    float h[16];
    #pragma unroll
    for (int n = 0; n < 16; ++n) h[n] = 0.f;
    float S = 0.f;

    size_t pd = (size_t)bl0 * DI + d;
    for (int t = 0; t < CL; ++t) {
        float dv = bf2f(Dh[pd]);
        float uv = bf2f(uh[pd]);
        float du = dv * uv;
        S += dv;
        float Bv[16];
        #pragma unroll
        for (int q = 0; q < 4; ++q)
            *(float4*)&Bv[q * 4] = *(const float4*)&Bs[t * 16 + q * 4];
        #pragma unroll
        for (int n = 0; n < 16; ++n) {
            float dA = __expf(dv * Adn[n]);
            h[n] = fmaf(dA, h[n], du * Bv[n]);
        }
        pd += DI;
    }

    size_t o = (((size_t)c * B_ + b) * DI + d) * DS;
    float aP[16];
    #pragma unroll
    for (int n = 0; n < 16; ++n) aP[n] = __expf(S * Adn[n]);
    #pragma unroll
    for (int q = 0; q < 4; ++q) {
        *(float4*)&sA[o + q * 4] = *(float4*)&aP[q * 4];
        *(float4*)&sH[o + q * 4] = *(float4*)&h[q * 4];
    }
}

static __device__ void dev_scanC(
    float* Bs, float* Cs, const ushort* __restrict__ Dh,
    const ushort* __restrict__ uh, const float* __restrict__ xdbl,
    const ushort* __restrict__ Zh, const float* __restrict__ A_log,
    const float* __restrict__ D_skip, const float* __restrict__ hinit,
    ushort* __restrict__ yh, int blk)
{
    const int tid  = threadIdx.x;
    const int dblk = blk & 7;
    const int c    = (blk >> 3) & (NC - 1);
    const int b    = blk >> 8;
    const int d    = dblk * 256 + tid;
    const int bl0  = b * L_ + c * CL;

    __syncthreads();
    for (int i = tid; i < CL * 16; i += 256) {
        int t = i >> 4, n = i & 15;
        size_t px = (size_t)(bl0 + t) * 96 + DR + n;
        Bs[t * 16 + n] = xdbl[px];
        Cs[t * 16 + n] = xdbl[px + DS];
    }
    __syncthreads();

    float Adn[16];
    #pragma unroll
    for (int q = 0; q < 4; ++q) {
        float4 al = *(const float4*)&A_log[d * DS + q * 4];
        Adn[q * 4 + 0] = -__expf(al.x);
        Adn[q * 4 + 1] = -__expf(al.y);
        Adn[q * 4 + 2] = -__expf(al.z);
        Adn[q * 4 + 3] = -__expf(al.w);
    }
    const float Dd = D_skip[d];

    float h[16];
    size_t o = (((size_t)c * B_ + b) * DI + d) * DS;
    #pragma unroll
    for (int q = 0; q < 4; ++q)
        *(float4*)&h[q * 4] = *(const float4*)&hinit[o + q * 4];

    size_t pd = (size_t)bl0 * DI + d;
    for (int t = 0; t < CL; ++t) {
        float dv = bf2f(Dh[pd]);
        float uv = bf2f(uh[pd]);
        float du = dv * uv;
        float Bv[16], Cv[16];
        #pragma unroll
        for (int q = 0; q < 4; ++q) {
            *(float4*)&Bv[q * 4] = *(const float4*)&Bs[t * 16 + q * 4];
            *(float4*)&Cv[q * 4] = *(const float4*)&Cs[t * 16 + q * 4];
        }
        float acc = 0.f;
        #pragma unroll
        for (int n = 0; n < 16; ++n) {
            float dA = __expf(dv * Adn[n]);
            h[n] = fmaf(dA, h[n], du * Bv[n]);
            acc = fmaf(h[n], Cv[n], acc);
        }
        float zv = bf2f(Zh[pd]);
        float yv = acc + Dd * uv;
        yv *= zv / (1.f + __expf(-zv));
        yh[pd] = f2bf(yv);
        pd += DI;
    }
}

// ---------------------------------------------------------------------------
// mega: the entire post-prep pipeline, grid-stride over logical blocks so it
// is correct for ANY grid size; launched cooperatively.
// ---------------------------------------------------------------------------
__global__ __launch_bounds__(256) void mega(
    const float* conv_w, const float* conv_b, const float* b_dt,
    const float* A_log, const float* D_skip,
    const ushort* Xh, const ushort* WIh,
    const ushort* WXh, const ushort* WXl,
    const ushort* WDh, const ushort* WDl, const ushort* Woh,
    float* Xin, ushort* Zh, ushort* Dh, float* xdbl, ushort* DTh,
    float* parts, ushort* Uh, float* sA, float* sH, float* hin,
    ushort* Yh, float* out)
{
    cg::grid_group grid = cg::this_grid();
    __shared__ ushort sm[24576];               // 48 KB arena, reused per phase
    const int blk = blockIdx.x;
    const int tid = threadIdx.x;
    const int G   = gridDim.x;

    // ---- Phase 0: xz = x @ W_in (1-term, split epi Xin fp32 | Zh bf16) ----
    for (int lb = blk; lb < 512; lb += G)
        dev_gemm<1, 2>(sm, Xh, WIh, nullptr, Xin, Zh, nullptr,
                       2048, 4096, DM, DM, 2048, DM,
                       (lb >> 5) * 128, (lb & 31) * 128, 0, 0);
    grid.sync();

    // ---- Phase 1: u = silu(conv(x_in)+b) -> bf16 hi ----
    for (int idx = blk * 256 + tid; idx < B_ * L_ * DI; idx += G * 256) {
        int d  = idx & (DI - 1);
        int bl = idx >> 11;
        int l  = bl & (L_ - 1);
        const float w0 = conv_w[d * 4 + 0], w1 = conv_w[d * 4 + 1];
        const float w2 = conv_w[d * 4 + 2], w3 = conv_w[d * 4 + 3];
        float s = conv_b[d];
        size_t base = (size_t)bl * 2048 + d;
        if (l >= 3) s = fmaf(w0, Xin[base - 3 * 2048], s);
        if (l >= 2) s = fmaf(w1, Xin[base - 2 * 2048], s);
        if (l >= 1) s = fmaf(w2, Xin[base - 1 * 2048], s);
        s = fmaf(w3, Xin[base], s);
        float v = s / (1.f + __expf(-s));
        Uh[idx] = f2bf(v);
    }
    grid.sync();

    // ---- Phase 2: x_dbl parts = u @ W_xproj (2-term, split-K x16) ----
    for (int lb = blk; lb < 256; lb += G)
        dev_gemm<2, 0>(sm, Uh, WXh, WXl, parts, nullptr, nullptr,
                       2048, 96, DI, DI, 96, 128,
                       (lb >> 4) * 128, 0, (lb & 15) * 128, lb & 15);
    grid.sync();

    // ---- Phase 3: reduce parts -> xdbl (+ DTh bf16) ----
    for (int i = blk * 256 + tid; i < 2048 * 96; i += G * 256) {
        float s = 0.f;
        #pragma unroll
        for (int c = 0; c < 16; ++c) s += parts[i + (size_t)c * (2048 * 96)];
        xdbl[i] = s;
        int row = i / 96, col = i - row * 96;
        if (col < 64) DTh[row * 64 + col] = f2bf(s);
    }
    grid.sync();

    // ---- Phase 4: delta = softplus(dt_lr @ W_dt + b_dt) -> Dh ----
    for (int lb = blk; lb < 256; lb += G)
        dev_gemm<2, 1>(sm, DTh, WDh, WDl, nullptr, Dh, b_dt,
                       2048, DI, DR, DR, DI, DR,
                       (lb >> 4) * 128, (lb & 15) * 128, 0, 0);
    grid.sync();

    // ---- Phase 5: scan partials ----
    for (int lb = blk; lb < 512; lb += G)
        dev_scanA((float*)sm, Dh, Uh, xdbl, A_log, sA, sH, lb);
    grid.sync();

    // ---- Phase 6: combine -> hinit ----
    for (int lb = blk; lb < 256; lb += G) {
        int idx = lb * 256 + tid;              // (b,d,n) over 65536
        int n = idx & 15;
        int d = (idx >> 4) & (DI - 1);
        int b = idx >> 15;
        float h = 0.f;
        #pragma unroll
        for (int c = 0; c < NC; ++c) {
            size_t o = (((size_t)c * B_ + b) * DI + d) * DS + n;
            hin[o] = h;
            h = fmaf(sA[o], h, sH[o]);
        }
    }
    grid.sync();

    // ---- Phase 7: scan final -> Yh ----
    for (int lb = blk; lb < 512; lb += G)
        dev_scanC((float*)sm, (float*)sm + 512, Dh, Uh, xdbl, Zh, A_log,
                  D_skip, hin, Yh, lb);
    grid.sync();

    // ---- Phase 8: out = y @ W_out (128x64, full-K, direct store) ----
    for (int lb = blk; lb < 256; lb += G)
        dev_gemm_out(sm, Yh, Woh, out, DI, DI, DI, DM,
                     (lb >> 4) * 128, (lb & 15) * 64);
}

// ---------------------------------------------------------------------------
// Fallback wrappers (proven round-12 10-dispatch path).
// ---------------------------------------------------------------------------
__global__ __launch_bounds__(256) void k_gemm1(
    const ushort* Xh, const ushort* WIh, float* Xin, ushort* Zh)
{
    __shared__ ushort sm[16384];
    dev_gemm<1, 2>(sm, Xh, WIh, nullptr, Xin, Zh, nullptr,
                   2048, 4096, DM, DM, 2048, DM,
                   blockIdx.y * 128, blockIdx.x * 128, 0, 0);
}

__global__ __launch_bounds__(256) void k_conv(
    const float* xin, const float* w, const float* bias, ushort* uh)
{
    int idx = blockIdx.x * 256 + threadIdx.x;
    if (idx >= B_ * L_ * DI) return;
    int d  = idx & (DI - 1);
    int bl = idx >> 11;
    int l  = bl & (L_ - 1);
    const float w0 = w[d * 4 + 0], w1 = w[d * 4 + 1];
    const float w2 = w[d * 4 + 2], w3 = w[d * 4 + 3];
    float s = bias[d];
    size_t base = (size_t)bl * 2048 + d;
    if (l >= 3) s = fmaf(w0, xin[base - 3 * 2048], s);
    if (l >= 2) s = fmaf(w1, xin[base - 2 * 2048], s);
    if (l >= 1) s = fmaf(w2, xin[base - 1 * 2048], s);
    s = fmaf(w3, xin[base], s);
    float v = s / (1.f + __expf(-s));
    uh[idx] = f2bf(v);
}

__global__ __launch_bounds__(256) void k_gemmX(
    const ushort* Uh, const ushort* WXh, const ushort* WXl, float* parts)
{
    __shared__ ushort sm[24576];
    dev_gemm<2, 0>(sm, Uh, WXh, WXl, parts, nullptr, nullptr,
                   2048, 96, DI, DI, 96, 128,
                   blockIdx.y * 128, 0, blockIdx.z * 128, blockIdx.z);
}

__global__ __launch_bounds__(256) void k_reduce(
    const float* p, float* xdbl, ushort* DTh)
{
    int i = blockIdx.x * 256 + threadIdx.x;
    if (i >= 2048 * 96) return;
    float s = 0.f;
    #pragma unroll
    for (int c = 0; c < 16; ++c) s += p[i + (size_t)c * (2048 * 96)];
    xdbl[i] = s;
    int row = i / 96, col = i - row * 96;
    if (col < 64) DTh[row * 64 + col] = f2bf(s);
}

__global__ __launch_bounds__(256) void k_gemmD(
    const ushort* DTh, const ushort* WDh, const ushort* WDl, ushort* Dh,
    const float* b_dt)
{
    __shared__ ushort sm[24576];
    dev_gemm<2, 1>(sm, DTh, WDh, WDl, nullptr, Dh, b_dt,
                   2048, DI, DR, DR, DI, DR,
                   blockIdx.y * 128, blockIdx.x * 128, 0, 0);
}

__global__ __launch_bounds__(256) void k_scanA(
    const ushort* Dh, const ushort* Uh, const float* xdbl, const float* A_log,
    float* sA, float* sH)
{
    __shared__ float Bs[512];
    dev_scanA(Bs, Dh, Uh, xdbl, A_log, sA, sH, blockIdx.x);
}

__global__ __launch_bounds__(256) void k_comb(
    const float* sA, const float* sH, float* hin)
{
    int idx = blockIdx.x * 256 + threadIdx.x;
    int n = idx & 15;
    int d = (idx >> 4) & (DI - 1);
    int b = idx >> 15;
    float h = 0.f;
    #pragma unroll
    for (int c = 0; c < NC; ++c) {
        size_t o = (((size_t)c * B_ + b) * DI + d) * DS + n;
        hin[o] = h;
        h = fmaf(sA[o], h, sH[o]);
    }
}

__global__ __launch_bounds__(256) void k_scanC(
    const ushort* Dh, const ushort* Uh, const float* xdbl, const ushort* Zh,
    const float* A_log, const float* D_skip, const float* hin, ushort* Yh)
{
    __shared__ float BsCs[1024];
    dev_scanC(BsCs, BsCs + 512, Dh, Uh, xdbl, Zh, A_log, D_skip, hin, Yh,
              blockIdx.x);
}

__global__ __launch_bounds__(256) void k_out(
    const ushort* Yh, const ushort* Woh, float* out)
{
    __shared__ ushort sm[12288];
    dev_gemm_out(sm, Yh, Woh, out, DI, DI, DI, DM,
                 blockIdx.y * 128, blockIdx.x * 64);
}

// ---------------------------------------------------------------------------
extern "C" void kernel_launch(void* const* d_in, const int* in_sizes, int n_in,
                              void* d_out, int out_size, void* d_ws, size_t ws_size,
                              hipStream_t stream)
{
    const float* x      = (const float*)d_in[0];
    const float* W_in   = (const float*)d_in[1];
    const float* conv_w = (const float*)d_in[2];
    const float* conv_b = (const float*)d_in[3];
    const float* W_xprj = (const float*)d_in[4];
    const float* W_dt   = (const float*)d_in[5];
    const float* b_dt   = (const float*)d_in[6];
    const float* A_log  = (const float*)d_in[7];
    const float* D_skip = (const float*)d_in[8];
    const float* W_out  = (const float*)d_in[9];
    float* out = (float*)d_out;

    char* ws = (char*)d_ws;
    float*  Xin   = (float*)(ws + 0);            // 16M fp32 x_in
    ushort* Zh    = (ushort*)(ws + 16777216);    // 8M  bf16 z
    ushort* Dh    = (ushort*)(ws + 33554432);    // 8M  delta bf16
    float*  xdbl  = (float*)(ws + 50331648);     // 768K
    ushort* Woh   = (ushort*)(ws + 51118080);    // 4M  (prep -> out-GEMM)
    // rotating region 57.4M..82.6M (handoffs barrier-separated):
    ushort* Xh    = (ushort*)(ws + 57409536);    // 4M
    float*  parts = (float*)(ws + 57409536);     // 12.6M (over Xh+WIh)
    ushort* WIh   = (ushort*)(ws + 65798144);    // 8M
    float*  sA    = (float*)(ws + 57409536);     // 8M
    float*  sH    = (float*)(ws + 65798144);     // 8M
    float*  hin   = (float*)(ws + 74186752);     // 8M
    ushort* Yh    = (ushort*)(ws + 57409536);    // 8M (over sA)
    ushort* Uh    = (ushort*)(ws + 82575360);    // 8M
    ushort* WXh   = (ushort*)(ws + 99352576);    // 512K
    ushort* WXl   = (ushort*)(ws + 99876864);    // 512K
    ushort* DTh   = (ushort*)(ws + 100401152);   // 256K
    ushort* WDh   = (ushort*)(ws + 100914176);   // 256K
    ushort* WDl   = (ushort*)(ws + 101170688);   // 256K (end 101427200)

    dim3 blk(256);

    // ---- dispatch 1: all input conversions ----
    prep_all<<<dim3(7552), blk, 0, stream>>>(
        x, W_in, W_xprj, W_dt, W_out, Xh, WIh, WXh, WXl, WDh, WDl, Woh);

    // ---- capacity pre-check (pure queries; deterministic) ----
    int dev = 0;
    hipGetDevice(&dev);
    int coop = 0;
    hipDeviceGetAttribute(&coop, hipDeviceAttributeCooperativeLaunch, dev);
    int occ = 0;
    hipOccupancyMaxActiveBlocksPerMultiprocessor(&occ, mega, 256, 0);
    int grid = occ * 256;
    if (grid > 512) grid = 512;

    if (coop && grid >= 256) {
        void* args[] = {
            (void*)&conv_w, (void*)&conv_b, (void*)&b_dt, (void*)&A_log,
            (void*)&D_skip, (void*)&Xh, (void*)&WIh, (void*)&WXh, (void*)&WXl,
            (void*)&WDh, (void*)&WDl, (void*)&Woh, (void*)&Xin, (void*)&Zh,
            (void*)&Dh, (void*)&xdbl, (void*)&DTh, (void*)&parts, (void*)&Uh,
            (void*)&sA, (void*)&sH, (void*)&hin, (void*)&Yh, (void*)&out
        };
        hipLaunchCooperativeKernel((void*)mega, dim3(grid), blk, args, 0, stream);
    } else {
        k_gemm1<<<dim3(32, 16), blk, 0, stream>>>(Xh, WIh, Xin, Zh);
        k_conv<<<dim3(16384), blk, 0, stream>>>(Xin, conv_w, conv_b, Uh);
        k_gemmX<<<dim3(1, 16, 16), blk, 0, stream>>>(Uh, WXh, WXl, parts);
        k_reduce<<<dim3(768), blk, 0, stream>>>(parts, xdbl, DTh);
        k_gemmD<<<dim3(16, 16), blk, 0, stream>>>(DTh, WDh, WDl, Dh, b_dt);
        k_scanA<<<dim3(512), blk, 0, stream>>>(Dh, Uh, xdbl, A_log, sA, sH);
        k_comb<<<dim3(256), blk, 0, stream>>>(sA, sH, hin);
        k_scanC<<<dim3(512), blk, 0, stream>>>(Dh, Uh, xdbl, Zh, A_log, D_skip, hin, Yh);
        k_out<<<dim3(16, 16), blk, 0, stream>>>(Yh, Woh, out);
    }
}

// Round 16
// 173.191 us; speedup vs baseline: 1.1709x; 1.1709x over previous
//
#include <hip/hip_runtime.h>
#include <cmath>

#define B_  2
#define L_  1024
#define DM  1024
#define DI  2048
#define DS  16
#define DR  64
#define NC  32         // scan time-chunks
#define CL  (L_/NC)    // 32 steps per chunk

typedef __attribute__((ext_vector_type(8))) short short8;
typedef __attribute__((ext_vector_type(4))) float f32x4;

static __device__ __forceinline__ ushort f2bf(float f) {
    union { float f; unsigned u; } c; c.f = f;
    unsigned u = c.u;
    return (ushort)((u + 0x7fffu + ((u >> 16) & 1u)) >> 16);   // RNE
}
static __device__ __forceinline__ float bf2f(ushort h) {
    union { unsigned u; float f; } c; c.u = ((unsigned)h) << 16;
    return c.f;
}

static __device__ __forceinline__ float softplus_f(float v) {
    return (v > 20.f) ? v : log1pf(__expf(v));
}

// ---------------------------------------------------------------------------
// bt_body: transpose-convert one 32x32 tile of fp32 [K][N] -> bf16 [N][K]
// (hi, and lo if ol != nullptr). Rows n >= N zero-padded to Npad.
// ---------------------------------------------------------------------------
static __device__ void bt_body(const float* __restrict__ in,
                               ushort* __restrict__ oh, ushort* __restrict__ ol,
                               int K, int N, int Npad, int bx, int by,
                               float (*t)[33])
{
    const int tid = threadIdx.x;
    const int tx = tid & 31, ty = tid >> 5;
    const int n0 = bx * 32, k0 = by * 32;
    #pragma unroll
    for (int i = 0; i < 4; ++i) {
        int k = k0 + ty * 4 + i, n = n0 + tx;
        t[ty * 4 + i][tx] = (n < N) ? in[(size_t)k * N + n] : 0.f;
    }
    __syncthreads();
    #pragma unroll
    for (int i = 0; i < 4; ++i) {
        int r = n0 + ty * 4 + i;
        int c = k0 + tx;
        if (r < Npad) {
            float v = t[tx][ty * 4 + i];
            ushort h = f2bf(v);
            oh[(size_t)r * K + c] = h;
            if (ol) ol[(size_t)r * K + c] = f2bf(v - bf2f(h));
        }
    }
}

// ---------------------------------------------------------------------------
// prep_all: ALL input conversions in one kernel.
//  [0,4096)     : W_in^T  hi only      (K=1024, N=4096)
//  [4096,4352)  : W_xproj^T hi/lo      (K=2048, N=96->128)
//  [4352,4480)  : W_dt^T hi/lo         (K=64,   N=2048)
//  [4480,5504)  : x -> bf16 hi rows
//  [5504,7552)  : W_out^T hi only      (K=2048, N=1024)
// ---------------------------------------------------------------------------
__global__ __launch_bounds__(256) void prep_all(
    const float* __restrict__ x, const float* __restrict__ W_in,
    const float* __restrict__ W_xprj, const float* __restrict__ W_dt,
    const float* __restrict__ W_out,
    ushort* __restrict__ Xh, ushort* __restrict__ WIh,
    ushort* __restrict__ WXh, ushort* __restrict__ WXl,
    ushort* __restrict__ WDh, ushort* __restrict__ WDl,
    ushort* __restrict__ Woh)
{
    __shared__ float t[32][33];
    int blk = blockIdx.x;
    if (blk < 4096) {
        bt_body(W_in, WIh, nullptr, 1024, 4096, 4096, blk & 127, blk >> 7, t);
    } else if (blk < 4352) {
        int b2 = blk - 4096;
        bt_body(W_xprj, WXh, WXl, 2048, 96, 128, b2 & 3, b2 >> 2, t);
    } else if (blk < 4480) {
        int b2 = blk - 4352;
        bt_body(W_dt, WDh, WDl, 64, 2048, 2048, b2 & 63, b2 >> 6, t);
    } else if (blk < 5504) {
        int v = (blk - 4480) * 256 + threadIdx.x;    // over 262144
        int r  = v >> 7;
        int c8 = v & 127;
        const float* p = x + (size_t)r * DM + c8 * 8;
        float4 v0 = *(const float4*)p;
        float4 v1 = *(const float4*)(p + 4);
        float vv[8] = {v0.x, v0.y, v0.z, v0.w, v1.x, v1.y, v1.z, v1.w};
        unsigned h[4];
        #pragma unroll
        for (int j = 0; j < 4; ++j)
            h[j] = (unsigned)f2bf(vv[2*j]) | ((unsigned)f2bf(vv[2*j+1]) << 16);
        size_t o = (size_t)r * 1024 + c8 * 8;
        *(uint4*)&Xh[o] = make_uint4(h[0], h[1], h[2], h[3]);
    } else {
        int b2 = blk - 5504;
        bt_body(W_out, Woh, nullptr, 2048, 1024, 1024, b2 & 31, b2 >> 5, t);
    }
}

// ---------------------------------------------------------------------------
// Shared GEMM building blocks. XOR-swizzle involution
// perm(a)=a^(((a>>7)&7)<<4) applied to BOTH gload source addr and frag read.
// ---------------------------------------------------------------------------
static __device__ __forceinline__ void stage_tile(
    ushort* lds, const ushort* __restrict__ g, int ld, int row0, int k0,
    int wid, int lane)
{
    #pragma unroll
    for (int it = 0; it < 2; ++it) {
        int o  = wid * 2048 + it * 1024;          // tile-local byte base
        int ob = o + lane * 16;
        int a  = ob ^ (((ob >> 7) & 7) << 4);     // logical byte address
        int row = a >> 6;
        int lc  = (a >> 4) & 3;
        const ushort* gp = g + (size_t)(row0 + row) * ld + k0 + lc * 8;
        __builtin_amdgcn_global_load_lds(
            (const __attribute__((address_space(1))) void*)gp,
            (__attribute__((address_space(3))) void*)((char*)lds + o),
            16, 0, 0);
    }
}

// 64-row tile (4KB): one 1KB gload per wave
static __device__ __forceinline__ void stage_tile64(
    ushort* lds, const ushort* __restrict__ g, int ld, int row0, int k0,
    int wid, int lane)
{
    int o  = wid * 1024;
    int ob = o + lane * 16;
    int a  = ob ^ (((ob >> 7) & 7) << 4);
    int row = a >> 6;
    int lc  = (a >> 4) & 3;
    const ushort* gp = g + (size_t)(row0 + row) * ld + k0 + lc * 8;
    __builtin_amdgcn_global_load_lds(
        (const __attribute__((address_space(1))) void*)gp,
        (__attribute__((address_space(3))) void*)((char*)lds + o),
        16, 0, 0);
}

static __device__ __forceinline__ short8 frag(const ushort* lds, int row, int fq) {
    int a = row * 64 + fq * 16;
    int b = a ^ (((a >> 7) & 7) << 4);
    return *(const short8*)((const char*)lds + b);
}

// ---------------------------------------------------------------------------
// gemm_bt: C[M][N] = A[M][K] @ B[N][K]^T, 128x128 tile, BK=32, 4 waves,
// double-buffered LDS. TERMS=1: Ah*Bh. TERMS=2: Ah*(Bh+Bl).
// EPI=0: fp32 store (+blockIdx.z*M row offset). EPI=1: softplus->bf16 hi/lo.
// ---------------------------------------------------------------------------
template<int TERMS>
static __device__ __forceinline__ void stage_all(
    ushort* buf, const ushort* Ah, const ushort* Bh, const ushort* Bl,
    int lda, int ldb, int bm, int bn, int k, int wid, int lane)
{
    stage_tile(buf,        Ah, lda, bm, k, wid, lane);
    stage_tile(buf + 4096, Bh, ldb, bn, k, wid, lane);
    if (TERMS == 2) stage_tile(buf + 8192, Bl, ldb, bn, k, wid, lane);
}

template<int TERMS>
static __device__ __forceinline__ void compute_tile(
    const ushort* buf, int wr, int wc, int fr, int fq, f32x4 acc[4][4])
{
    const ushort* sAh = buf;
    const ushort* sBh = buf + 4096;
    const ushort* sBl = buf + 8192;
    short8 a_h[4], b_h[4], b_l[4];
    #pragma unroll
    for (int m = 0; m < 4; ++m)
        a_h[m] = frag(sAh, wr + m * 16 + fr, fq);
    #pragma unroll
    for (int n = 0; n < 4; ++n) {
        b_h[n] = frag(sBh, wc + n * 16 + fr, fq);
        if (TERMS == 2) b_l[n] = frag(sBl, wc + n * 16 + fr, fq);
    }
    #pragma unroll
    for (int m = 0; m < 4; ++m)
        #pragma unroll
        for (int n = 0; n < 4; ++n) {
            acc[m][n] = __builtin_amdgcn_mfma_f32_16x16x32_bf16(a_h[m], b_h[n], acc[m][n], 0, 0, 0);
            if (TERMS == 2)
                acc[m][n] = __builtin_amdgcn_mfma_f32_16x16x32_bf16(a_h[m], b_l[n], acc[m][n], 0, 0, 0);
        }
}

template<int TERMS, int EPI>
__global__ __launch_bounds__(256) void gemm_bt(
    const ushort* __restrict__ Ah,
    const ushort* __restrict__ Bh, const ushort* __restrict__ Bl,
    float* __restrict__ C, ushort* __restrict__ oh, ushort* __restrict__ ol,
    const float* __restrict__ bvec,
    int M, int N, int lda, int ldb, int ldc, int kspl)
{
    constexpr int TILE = TERMS == 1 ? 8192 : 12288;   // ushorts per buffer
    __shared__ ushort sm[2 * TILE];

    const int tid = threadIdx.x, wid = tid >> 6, lane = tid & 63;
    const int bm = blockIdx.y * 128, bn = blockIdx.x * 128;
    const int kb = blockIdx.z * kspl;
    const int wr = (wid >> 1) * 64, wc = (wid & 1) * 64;
    const int fr = lane & 15, fq = lane >> 4;

    f32x4 acc[4][4] = {};

    stage_all<TERMS>(sm, Ah, Bh, Bl, lda, ldb, bm, bn, kb, wid, lane);
    __syncthreads();
    int cur = 0;
    for (int k0 = 32; k0 < kspl; k0 += 32) {
        ushort* nbuf       = cur ? sm : sm + TILE;
        const ushort* cbuf = cur ? sm + TILE : sm;
        stage_all<TERMS>(nbuf, Ah, Bh, Bl, lda, ldb, bm, bn, kb + k0, wid, lane);
        compute_tile<TERMS>(cbuf, wr, wc, fr, fq, acc);
        __syncthreads();
        cur ^= 1;
    }
    compute_tile<TERMS>(cur ? sm + TILE : sm, wr, wc, fr, fq, acc);

    #pragma unroll
    for (int m = 0; m < 4; ++m) {
        int rbase = bm + wr + m * 16 + fq * 4;
        #pragma unroll
        for (int n = 0; n < 4; ++n) {
            int col = bn + wc + n * 16 + fr;
            if (col >= N) continue;
            if (EPI == 0) {
                #pragma unroll
                for (int j = 0; j < 4; ++j)
                    C[((size_t)blockIdx.z * M + rbase + j) * ldc + col] = acc[m][n][j];
            } else {
                float bb = bvec[col];
                #pragma unroll
                for (int j = 0; j < 4; ++j)
                    oh[(size_t)(rbase + j) * ldc + col] =
                        f2bf(softplus_f(acc[m][n][j] + bb));
            }
        }
    }
}

// ---------------------------------------------------------------------------
// gemm_out64: C[M][N] = A[M][K] @ B[N][K]^T, 128x64 tile, full-K, 1-term,
// direct fp32 store. Grid (N/64, M/128) = 256 blocks.
// ---------------------------------------------------------------------------
__global__ __launch_bounds__(256) void gemm_out64(
    const ushort* __restrict__ Ah, const ushort* __restrict__ Bh,
    float* __restrict__ C, int K, int lda, int ldb, int ldc)
{
    __shared__ ushort sm[12288];                  // 24 KB: two 12 KB buffers
    const int tid = threadIdx.x, wid = tid >> 6, lane = tid & 63;
    const int bm = blockIdx.y * 128, bn = blockIdx.x * 64;
    const int wr = (wid >> 1) * 64, wc = (wid & 1) * 32;
    const int fr = lane & 15, fq = lane >> 4;

    f32x4 acc[4][2] = {};

    stage_tile  (sm,        Ah, lda, bm, 0, wid, lane);
    stage_tile64(sm + 4096, Bh, ldb, bn, 0, wid, lane);
    __syncthreads();
    int cur = 0;
    for (int k0 = 32; k0 < K; k0 += 32) {
        ushort* nbuf       = cur ? sm : sm + 6144;
        const ushort* cbuf = cur ? sm + 6144 : sm;
        stage_tile  (nbuf,        Ah, lda, bm, k0, wid, lane);
        stage_tile64(nbuf + 4096, Bh, ldb, bn, k0, wid, lane);
        {
            short8 a_h[4], b_h[2];
            #pragma unroll
            for (int m = 0; m < 4; ++m)
                a_h[m] = frag(cbuf, wr + m * 16 + fr, fq);
            #pragma unroll
            for (int n = 0; n < 2; ++n)
                b_h[n] = frag(cbuf + 4096, wc + n * 16 + fr, fq);
            #pragma unroll
            for (int m = 0; m < 4; ++m)
                #pragma unroll
                for (int n = 0; n < 2; ++n)
                    acc[m][n] = __builtin_amdgcn_mfma_f32_16x16x32_bf16(a_h[m], b_h[n], acc[m][n], 0, 0, 0);
        }
        __syncthreads();
        cur ^= 1;
    }
    {
        const ushort* cbuf = cur ? sm + 6144 : sm;
        short8 a_h[4], b_h[2];
        #pragma unroll
        for (int m = 0; m < 4; ++m)
            a_h[m] = frag(cbuf, wr + m * 16 + fr, fq);
        #pragma unroll
        for (int n = 0; n < 2; ++n)
            b_h[n] = frag(cbuf + 4096, wc + n * 16 + fr, fq);
        #pragma unroll
        for (int m = 0; m < 4; ++m)
            #pragma unroll
            for (int n = 0; n < 2; ++n)
                acc[m][n] = __builtin_amdgcn_mfma_f32_16x16x32_bf16(a_h[m], b_h[n], acc[m][n], 0, 0, 0);
    }

    #pragma unroll
    for (int m = 0; m < 4; ++m) {
        int rbase = bm + wr + m * 16 + fq * 4;
        #pragma unroll
        for (int n = 0; n < 2; ++n) {
            int col = bn + wc + n * 16 + fr;
            #pragma unroll
            for (int j = 0; j < 4; ++j)
                C[(size_t)(rbase + j) * ldc + col] = acc[m][n][j];
        }
    }
}

// ---------------------------------------------------------------------------
// reduce_xproj: sum 16 split-K parts -> xdbl; also emit dt_lr as bf16 hi.
// ---------------------------------------------------------------------------
__global__ __launch_bounds__(256) void reduce_xproj(
    const float* __restrict__ p, float* __restrict__ xdbl,
    ushort* __restrict__ DTh)
{
    int i = blockIdx.x * 256 + threadIdx.x;
    if (i >= 2048 * 96) return;
    float s = 0.f;
    #pragma unroll
    for (int c = 0; c < 16; ++c) s += p[i + (size_t)c * (2048 * 96)];
    xdbl[i] = s;
    int row = i / 96, col = i - row * 96;
    if (col < 64) DTh[row * 64 + col] = f2bf(s);
}

// ---------------------------------------------------------------------------
// Depthwise causal conv (k=4) + bias + SiLU -> u as bf16 hi only.
// ---------------------------------------------------------------------------
__global__ __launch_bounds__(256) void conv_silu(
    const float* __restrict__ xz, const float* __restrict__ w,
    const float* __restrict__ bias, ushort* __restrict__ uh)
{
    int idx = blockIdx.x * 256 + threadIdx.x;
    if (idx >= B_ * L_ * DI) return;
    int d  = idx & (DI - 1);
    int bl = idx >> 11;
    int l  = bl & (L_ - 1);

    const float w0 = w[d * 4 + 0], w1 = w[d * 4 + 1];
    const float w2 = w[d * 4 + 2], w3 = w[d * 4 + 3];
    float s = bias[d];
    size_t base = (size_t)bl * 4096 + d;
    if (l >= 3) s = fmaf(w0, xz[base - 3 * 4096], s);
    if (l >= 2) s = fmaf(w1, xz[base - 2 * 4096], s);
    if (l >= 1) s = fmaf(w2, xz[base - 1 * 4096], s);
    s = fmaf(w3, xz[base], s);
    float v = s / (1.f + __expf(-s));
    uh[idx] = f2bf(v);
}

// ---------------------------------------------------------------------------
// Scan phase A: lane owns channel d for chunk c. h[16], Adn[16] in regs.
// ---------------------------------------------------------------------------
__global__ __launch_bounds__(256) void scan_partial(
    const ushort* __restrict__ Dh, const ushort* __restrict__ Dl,
    const ushort* __restrict__ uh,
    const float* __restrict__ xdbl, const float* __restrict__ A_log,
    float* __restrict__ sA, float* __restrict__ sH)
{
    __shared__ float Bs[CL][16];
    const int tid  = threadIdx.x;
    const int dblk = blockIdx.x & 7;
    const int c    = (blockIdx.x >> 3) & (NC - 1);
    const int b    = blockIdx.x >> 8;
    const int d    = dblk * 256 + tid;
    const int bl0  = b * L_ + c * CL;

    for (int i = tid; i < CL * 16; i += 256) {
        int t = i >> 4, n = i & 15;
        Bs[t][n] = xdbl[(size_t)(bl0 + t) * 96 + DR + n];
    }
    __syncthreads();

    float Adn[16];
    #pragma unroll
    for (int q = 0; q < 4; ++q) {
        float4 al = *(const float4*)&A_log[d * DS + q * 4];
        Adn[q * 4 + 0] = -__expf(al.x);
        Adn[q * 4 + 1] = -__expf(al.y);
        Adn[q * 4 + 2] = -__expf(al.z);
        Adn[q * 4 + 3] = -__expf(al.w);
    }
    float h[16];
    #pragma unroll
    for (int n = 0; n < 16; ++n) h[n] = 0.f;
    float S = 0.f;

    size_t pd = (size_t)bl0 * DI + d;
    for (int t = 0; t < CL; ++t) {
        float dv = bf2f(Dh[pd]) + bf2f(Dl[pd]);
        float uv = bf2f(uh[pd]);
        float du = dv * uv;
        S += dv;
        float Bv[16];
        *(float4*)&Bv[0]  = *(const float4*)&Bs[t][0];
        *(float4*)&Bv[4]  = *(const float4*)&Bs[t][4];
        *(float4*)&Bv[8]  = *(const float4*)&Bs[t][8];
        *(float4*)&Bv[12] = *(const float4*)&Bs[t][12];
        #pragma unroll
        for (int n = 0; n < 16; ++n) {
            float dA = __expf(dv * Adn[n]);
            h[n] = fmaf(dA, h[n], du * Bv[n]);
        }
        pd += DI;
    }

    size_t o = (((size_t)c * B_ + b) * DI + d) * DS;
    float aP[16], hh[16];
    #pragma unroll
    for (int n = 0; n < 16; ++n) { aP[n] = __expf(S * Adn[n]); hh[n] = h[n]; }
    #pragma unroll
    for (int q = 0; q < 4; ++q) {
        *(float4*)&sA[o + q * 4] = *(float4*)&aP[q * 4];
        *(float4*)&sH[o + q * 4] = *(float4*)&hh[q * 4];
    }
}

// ---------------------------------------------------------------------------
__global__ __launch_bounds__(256) void scan_combine(
    const float* __restrict__ sA, const float* __restrict__ sH,
    float* __restrict__ hinit)
{
    int idx = blockIdx.x * 256 + threadIdx.x;   // (b,d,n)
    int n = idx & 15;
    int d = (idx >> 4) & (DI - 1);
    int b = idx >> 15;
    float h = 0.f;
    #pragma unroll
    for (int c = 0; c < NC; ++c) {
        size_t o = (((size_t)c * B_ + b) * DI + d) * DS + n;
        hinit[o] = h;
        h = fmaf(sA[o], h, sH[o]);
    }
}

// ---------------------------------------------------------------------------
// Scan phase C: rescan chunk from h_init; y-dot in regs; skip + z-gate
// fused; writes y as bf16 HI (GEMM_out A-operand).
// ---------------------------------------------------------------------------
__global__ __launch_bounds__(256) void scan_final(
    const ushort* __restrict__ Dh, const ushort* __restrict__ Dl,
    const ushort* __restrict__ uh,
    const float* __restrict__ xdbl, const float* __restrict__ xz,
    const float* __restrict__ A_log, const float* __restrict__ D_skip,
    const float* __restrict__ hinit, ushort* __restrict__ yh)
{
    __shared__ float Bs[CL][16];
    __shared__ float Cs[CL][16];
    const int tid  = threadIdx.x;
    const int dblk = blockIdx.x & 7;
    const int c    = (blockIdx.x >> 3) & (NC - 1);
    const int b    = blockIdx.x >> 8;
    const int d    = dblk * 256 + tid;
    const int bl0  = b * L_ + c * CL;

    for (int i = tid; i < CL * 16; i += 256) {
        int t = i >> 4, n = i & 15;
        size_t px = (size_t)(bl0 + t) * 96 + DR + n;
        Bs[t][n] = xdbl[px];
        Cs[t][n] = xdbl[px + DS];
    }
    __syncthreads();

    float Adn[16];
    #pragma unroll
    for (int q = 0; q < 4; ++q) {
        float4 al = *(const float4*)&A_log[d * DS + q * 4];
        Adn[q * 4 + 0] = -__expf(al.x);
        Adn[q * 4 + 1] = -__expf(al.y);
        Adn[q * 4 + 2] = -__expf(al.z);
        Adn[q * 4 + 3] = -__expf(al.w);
    }
    const float Dd = D_skip[d];

    float h[16];
    size_t o = (((size_t)c * B_ + b) * DI + d) * DS;
    #pragma unroll
    for (int q = 0; q < 4; ++q)
        *(float4*)&h[q * 4] = *(const float4*)&hinit[o + q * 4];

    size_t pd = (size_t)bl0 * DI + d;
    size_t pz = (size_t)bl0 * 4096 + 2048 + d;
    for (int t = 0; t < CL; ++t) {
        float dv = bf2f(Dh[pd]) + bf2f(Dl[pd]);
        float uv = bf2f(uh[pd]);
        float du = dv * uv;
        float Bv[16], Cv[16];
        *(float4*)&Bv[0]  = *(const float4*)&Bs[t][0];
        *(float4*)&Bv[4]  = *(const float4*)&Bs[t][4];
        *(float4*)&Bv[8]  = *(const float4*)&Bs[t][8];
        *(float4*)&Bv[12] = *(const float4*)&Bs[t][12];
        *(float4*)&Cv[0]  = *(const float4*)&Cs[t][0];
        *(float4*)&Cv[4]  = *(const float4*)&Cs[t][4];
        *(float4*)&Cv[8]  = *(const float4*)&Cs[t][8];
        *(float4*)&Cv[12] = *(const float4*)&Cs[t][12];
        float acc = 0.f;
        #pragma unroll
        for (int n = 0; n < 16; ++n) {
            float dA = __expf(dv * Adn[n]);
            h[n] = fmaf(dA, h[n], du * Bv[n]);
            acc = fmaf(h[n], Cv[n], acc);
        }
        float zv = xz[pz];
        float yv = acc + Dd * uv;
        yv *= zv / (1.f + __expf(-zv));
        yh[pd] = f2bf(yv);
        pd += DI; pz += 4096;
    }
}

// ---------------------------------------------------------------------------
extern "C" void kernel_launch(void* const* d_in, const int* in_sizes, int n_in,
                              void* d_out, int out_size, void* d_ws, size_t ws_size,
                              hipStream_t stream)
{
    const float* x      = (const float*)d_in[0];
    const float* W_in   = (const float*)d_in[1];
    const float* conv_w = (const float*)d_in[2];
    const float* conv_b = (const float*)d_in[3];
    const float* W_xprj = (const float*)d_in[4];
    const float* W_dt   = (const float*)d_in[5];
    const float* b_dt   = (const float*)d_in[6];
    const float* A_log  = (const float*)d_in[7];
    const float* D_skip = (const float*)d_in[8];
    const float* W_out  = (const float*)d_in[9];
    float* out = (float*)d_out;

    char* ws = (char*)d_ws;
    float*  xz    = (float*)(ws + 0);            // 32M (live gemm1->scan_final)
    ushort* Dh    = (ushort*)(ws + 33554432);    // 8M  } softplus'd delta
    ushort* Dl    = (ushort*)(ws + 41943040);    // 8M  }
    float*  xdbl  = (float*)(ws + 50331648);     // 768K (ends 51118080)
    ushort* Woh   = (ushort*)(ws + 51118080);    // 4M  (prep -> gemm_out; gap,
                                                 //      no intermediate writer)
    // rotating region 57.4M..82.6M:
    ushort* Xh    = (ushort*)(ws + 57409536);    // 4M  (prep -> gemm1)
    float*  parts = (float*)(ws + 57409536);     // 12.6M (xproj split-K x16,
                                                 //      over Xh+WIh, both dead)
    ushort* WIh   = (ushort*)(ws + 65798144);    // 8M  (prep -> gemm1)
    float*  sA    = (float*)(ws + 57409536);     // 8M  (scan)
    float*  sH    = (float*)(ws + 65798144);     // 8M
    float*  hin   = (float*)(ws + 74186752);     // 8M (end 82575360)
    ushort* Yh    = (ushort*)(ws + 57409536);    // 8M  (scan_final out, over sA)
    ushort* Uh    = (ushort*)(ws + 82575360);    // 8M
    ushort* WXh   = (ushort*)(ws + 99352576);    // 512K
    ushort* WXl   = (ushort*)(ws + 99876864);    // 512K
    ushort* DTh   = (ushort*)(ws + 100401152);   // 256K
    ushort* WDh   = (ushort*)(ws + 100914176);   // 256K
    ushort* WDl   = (ushort*)(ws + 101170688);   // 256K (end 101427200 = proven cap)

    dim3 blk(256);
    const int M = B_ * L_;   // 2048

    // ---- ALL input conversions (incl. W_out^T) ----
    prep_all<<<dim3(7552), blk, 0, stream>>>(
        x, W_in, W_xprj, W_dt, W_out, Xh, WIh, WXh, WXl, WDh, WDl, Woh);

    // ---- xz = x @ W_in : 1-term bf16 ----
    gemm_bt<1, 0><<<dim3(32, 16, 1), blk, 0, stream>>>(
        Xh, WIh, nullptr, xz, nullptr, nullptr, nullptr,
        M, 4096, DM, DM, 4096, DM);

    // ---- u = silu(conv(x_in)+b) -> bf16 hi ----
    conv_silu<<<dim3((B_ * L_ * DI) / 256), blk, 0, stream>>>(xz, conv_w, conv_b, Uh);

    // ---- x_dbl = u @ W_xproj : 2-term, split-K x16 (full occupancy) ----
    gemm_bt<2, 0><<<dim3(1, 16, 16), blk, 0, stream>>>(
        Uh, WXh, WXl, parts, nullptr, nullptr, nullptr,
        M, 96, DI, DI, 96, 128);
    reduce_xproj<<<dim3(768), blk, 0, stream>>>(parts, xdbl, DTh);

    // ---- delta = softplus(dt_lr @ W_dt + b_dt) : 2-term, fused epi ----
    gemm_bt<2, 1><<<dim3(16, 16, 1), blk, 0, stream>>>(
        DTh, WDh, WDl, nullptr, Dh, Dl, b_dt,
        M, DI, DR, DR, DI, DR);

    // ---- chunked selective scan ----
    scan_partial<<<dim3(B_ * NC * 8), blk, 0, stream>>>(
        Dh, Dl, Uh, xdbl, A_log, sA, sH);
    scan_combine<<<dim3((B_ * DI * DS) / 256), blk, 0, stream>>>(sA, sH, hin);
    scan_final<<<dim3(B_ * NC * 8), blk, 0, stream>>>(
        Dh, Dl, Uh, xdbl, xz, A_log, D_skip, hin, Yh);

    // ---- out = y @ W_out : 128x64 tile, full-K, direct store ----
    gemm_out64<<<dim3(DM / 64, M / 128), blk, 0, stream>>>(
        Yh, Woh, out, DI, DI, DI, DM);
}